// Round 6
// baseline (1017.461 us; speedup 1.0000x reference)
//
#include <hip/hip_runtime.h>
#include <cstdint>

typedef unsigned int uint;
typedef unsigned short ushort;
typedef __attribute__((ext_vector_type(8))) __bf16 bf16x8;
typedef __attribute__((ext_vector_type(4))) float f32x4;
typedef __attribute__((ext_vector_type(4))) ushort us4;

#define BB 16
#define TT 2048
#define DD 1024
#define HH 512
// GEMM: M = 32768, N = 3072, K = 1024

// ---------------------------------------------------------------------------
// helpers
// ---------------------------------------------------------------------------
__device__ inline ushort f2bf(float f) {
    uint u = __float_as_uint(f);
    u += 0x7FFF + ((u >> 16) & 1);  // RNE
    return (ushort)(u >> 16);
}
__device__ inline float bf2f(ushort b) {
    return __uint_as_float(((uint)b) << 16);
}
__device__ inline float sigm(float x) { return 1.f / (1.f + __expf(-x)); }
__device__ inline float4 ld4(const float* p) { return *(const float4*)p; }

__device__ inline void gload16(const void* g, void* l) {
    __builtin_amdgcn_global_load_lds(
        (const __attribute__((address_space(1))) uint*)g,
        (__attribute__((address_space(3))) uint*)l, 16, 0, 0);
}

// ---------------------------------------------------------------------------
// W (D,2,H,3) f32 -> Bth, Btl bf16 [N=3072][K=1024] (transposed, hi/lo split)
// n = z*1536 + gate*512 + h ;  Bt[n][d] = W[d][z][h][gate]
// ---------------------------------------------------------------------------
__global__ __launch_bounds__(256) void convert_W(const float* __restrict__ W,
                                                 ushort* __restrict__ Bth,
                                                 ushort* __restrict__ Btl) {
    int idx = blockIdx.x * 256 + threadIdx.x;  // 0 .. 3,145,727
    int d   = idx & 1023;
    int n   = idx >> 10;
    int z    = n / 1536;
    int rem  = n % 1536;
    int gate = rem >> 9;
    int h    = rem & 511;
    float w    = W[(size_t)d * 3072 + z * 1536 + h * 3 + gate];
    ushort whi = f2bf(w);
    Bth[idx]   = whi;
    Btl[idx]   = f2bf(w - bf2f(whi));
}

// ---------------------------------------------------------------------------
// split-bf16 MFMA GEMM with fused A conversion + A-prefetch (T14-lite).
// C[M][3072] ~= (Ah+Al)(Bh+Bl)  (Ah·Bh + Ah·Bl + Al·Bh; Al·Bl dropped)
// 128x128 tile, BK=32, 256 threads = 4 waves (2x2), each wave 64x64 = 4x4
// 16x16x32 fragments, 3 MFMA per fragment pair.
// LDS: Ah | Al | Bh | Bl, each [128][32] bf16, 16B chunks XOR-swizzled by
// ((row>>1)&3) on both write and read (cancels logically; ds_read_b128 is
// 2-way bank aliased = free; measured 0 bank conflicts in r5).
// ---------------------------------------------------------------------------
__global__ __launch_bounds__(256, 2) void gemm_bf16split(
    const float* __restrict__ x, const ushort* __restrict__ Bth,
    const ushort* __restrict__ Btl, float* __restrict__ C) {
    __shared__ ushort lds[4 * 128 * 32];  // 32 KB

    const int t    = threadIdx.x;
    const int w    = t >> 6;
    const int lane = t & 63;
    const size_t m0 = (size_t)blockIdx.x * 128;
    const size_t n0 = (size_t)blockIdx.y * 128;
    const int wm = w >> 1, wn = w & 1;

    f32x4 acc[4][4];
#pragma unroll
    for (int i = 0; i < 4; i++)
#pragma unroll
        for (int j = 0; j < 4; j++) acc[i][j] = (f32x4)(0.f);

    const int srow  = w * 32 + (lane >> 2);
    const int kphys = lane & 3;
    const int frow  = lane & 15;
    const int fkoff = (((lane >> 4) ^ ((frow >> 1) & 3)) << 3);  // ushort off

    // preload A regs for k0 = 0
    float4 xv[4];
#pragma unroll
    for (int p = 0; p < 4; p++) {
        int ridx = p * 256 + t;
        int row  = ridx >> 3;
        int kq   = ridx & 7;
        xv[p] = ld4(x + (m0 + row) * 1024 + kq * 4);
    }

    for (int k0 = 0; k0 < 1024; k0 += 32) {
        // ---- B tiles: async global->LDS, pre-swizzled source ----
#pragma unroll
        for (int arr = 0; arr < 2; arr++) {
            const ushort* G = arr ? Btl : Bth;
#pragma unroll
            for (int c = 0; c < 2; c++) {
                const int row = srow + c * 16;
                const int kcl = kphys ^ ((row >> 1) & 3);
                const ushort* src = G + ((n0 + row) << 10) + k0 + (kcl << 3);
                char* dst = (char*)lds + (2 + arr) * 8192 +
                            (w * 32 + c * 16) * 64 + lane * 16;
                gload16(src, dst);
            }
        }
        // ---- convert current A regs to hi/lo bf16, swizzled ds_write ----
#pragma unroll
        for (int p = 0; p < 4; p++) {
            int ridx = p * 256 + t;
            int row  = ridx >> 3;
            int kq   = ridx & 7;
            int off  = row * 64 + (((kq >> 1) ^ ((row >> 1) & 3)) << 4) +
                       ((kq & 1) << 3);
            float vf[4] = {xv[p].x, xv[p].y, xv[p].z, xv[p].w};
            us4 hi, lo;
#pragma unroll
            for (int j = 0; j < 4; j++) {
                ushort h = f2bf(vf[j]);
                hi[j]    = h;
                lo[j]    = f2bf(vf[j] - bf2f(h));
            }
            *(us4*)((char*)lds + off)        = hi;
            *(us4*)((char*)lds + 8192 + off) = lo;
        }
        __syncthreads();  // drains lgkm (ds_write) + vm (global_load_lds)

        bf16x8 fa[4], fal[4], fb[4], fbl[4];
#pragma unroll
        for (int i = 0; i < 4; i++) {
            const int ra = (wm * 64 + i * 16 + frow) * 32;
            const int rb = (wn * 64 + i * 16 + frow) * 32;
            fa[i]  = *(const bf16x8*)&lds[0 * 4096 + ra + fkoff];
            fal[i] = *(const bf16x8*)&lds[1 * 4096 + ra + fkoff];
            fb[i]  = *(const bf16x8*)&lds[2 * 4096 + rb + fkoff];
            fbl[i] = *(const bf16x8*)&lds[3 * 4096 + rb + fkoff];
        }

        // ---- prefetch next K-step's A regs; latency hides under MFMAs ----
        const int k0n = (k0 + 32) & 1023;  // wraps to 0 on last iter (safe)
        float4 xn[4];
#pragma unroll
        for (int p = 0; p < 4; p++) {
            int ridx = p * 256 + t;
            int row  = ridx >> 3;
            int kq   = ridx & 7;
            xn[p] = ld4(x + (m0 + row) * 1024 + k0n + kq * 4);
        }

#pragma unroll
        for (int i = 0; i < 4; i++)
#pragma unroll
            for (int j = 0; j < 4; j++) {
                acc[i][j] = __builtin_amdgcn_mfma_f32_16x16x32_bf16(
                    fa[i], fb[j], acc[i][j], 0, 0, 0);
                acc[i][j] = __builtin_amdgcn_mfma_f32_16x16x32_bf16(
                    fa[i], fbl[j], acc[i][j], 0, 0, 0);
                acc[i][j] = __builtin_amdgcn_mfma_f32_16x16x32_bf16(
                    fal[i], fb[j], acc[i][j], 0, 0, 0);
            }
        __syncthreads();  // protect LDS before next stage
#pragma unroll
        for (int p = 0; p < 4; p++) xv[p] = xn[p];
    }

    // epilogue: C/D layout col=lane&15 (n), row=(lane>>4)*4+reg (m)
    const int ccol = lane & 15;
    const int crow = (lane >> 4) * 4;
#pragma unroll
    for (int i = 0; i < 4; i++) {
        const size_t mrow = m0 + wm * 64 + i * 16 + crow;
#pragma unroll
        for (int j = 0; j < 4; j++) {
            const size_t ncol = n0 + wn * 64 + j * 16 + ccol;
            float* Cp = C + mrow * 3072 + ncol;
#pragma unroll
            for (int r = 0; r < 4; r++) Cp[(size_t)r * 3072] = acc[i][j][r];
        }
    }
}

// ---------------------------------------------------------------------------
// Scan, vectorized 4 channels/thread (float4). 32 chunks of 64 steps.
// Thread map: tid = s*4096 + ci; ci = b*256 + z*128 + (h4/4); ch4 = 4*ci.
// U[(b*T+t)*3072 + z*1536 + gate*512 + h], gate 0=g 1=f 2=r.
// logical step n; physical t = z ? T-1-n : n.
// ---------------------------------------------------------------------------
#define SCH 16384
#define NCH 32
#define CL 64

#define STEPA(CC, FA, G, FP, BF)          \
    {                                     \
        float ff = sigm((FP) + (BF));     \
        CC = ff * CC + (1.f - ff) * (G);  \
        FA *= ff;                         \
    }

#define STEPC(CC, G, FP, RP, XV, BF, BR, OUT)       \
    {                                               \
        float ff = sigm((FP) + (BF));               \
        float rr = sigm((RP) + (BR));               \
        CC = ff * CC + (1.f - ff) * (G);            \
        float e  = __expf(2.f * CC);                \
        float th = 1.f - 2.f / (e + 1.f);           \
        OUT = rr * th + (1.f - rr) * (XV);          \
    }

__global__ __launch_bounds__(256) void scanA(const float* __restrict__ U,
                                             const float* __restrict__ bias,
                                             float* __restrict__ F,
                                             float* __restrict__ Cp) {
    int tid = blockIdx.x * 256 + threadIdx.x;  // 0..131071
    int s   = tid >> 12;
    int ci  = tid & 4095;
    int b = ci >> 8, z = (ci >> 7) & 1, h4 = (ci & 127) << 2;
    float4 bf = ld4(&bias[z * 1024 + h4]);
    const float* Ub = U + (size_t)b * TT * 3072 + z * 1536 + h4;
    float4 c  = {0.f, 0.f, 0.f, 0.f};
    float4 Fa = {1.f, 1.f, 1.f, 1.f};
#pragma unroll 4
    for (int q = 0; q < CL; q++) {
        int n = s * CL + q;
        int t = z ? (TT - 1 - n) : n;
        size_t o = (size_t)t * 3072;
        float4 g = ld4(Ub + o);
        float4 f = ld4(Ub + o + 512);
        STEPA(c.x, Fa.x, g.x, f.x, bf.x);
        STEPA(c.y, Fa.y, g.y, f.y, bf.y);
        STEPA(c.z, Fa.z, g.z, f.z, bf.z);
        STEPA(c.w, Fa.w, g.w, f.w, bf.w);
    }
    *(float4*)&F[((size_t)s << 14) + (ci << 2)]  = Fa;
    *(float4*)&Cp[((size_t)s << 14) + (ci << 2)] = c;
}

__global__ __launch_bounds__(256) void scanB(const float* __restrict__ F,
                                             const float* __restrict__ Cp,
                                             float* __restrict__ cstart) {
    int ci = blockIdx.x * 256 + threadIdx.x;  // 0..4095
    float4 c = {0.f, 0.f, 0.f, 0.f};
    for (int s = 0; s < NCH; s++) {
        size_t o = ((size_t)s << 14) + (ci << 2);
        *(float4*)&cstart[o] = c;
        float4 Fv = ld4(&F[o]);
        float4 Cv = ld4(&Cp[o]);
        c.x = Fv.x * c.x + Cv.x;
        c.y = Fv.y * c.y + Cv.y;
        c.z = Fv.z * c.z + Cv.z;
        c.w = Fv.w * c.w + Cv.w;
    }
}

__global__ __launch_bounds__(256) void scanC(const float* __restrict__ U,
                                             const float* __restrict__ x,
                                             const float* __restrict__ bias,
                                             const float* __restrict__ cstart,
                                             float* __restrict__ out) {
    int tid = blockIdx.x * 256 + threadIdx.x;  // 0..131071
    int s   = tid >> 12;
    int ci  = tid & 4095;
    int b = ci >> 8, z = (ci >> 7) & 1, h4 = (ci & 127) << 2;
    float4 bf = ld4(&bias[z * 1024 + h4]);
    float4 br = ld4(&bias[z * 1024 + 512 + h4]);
    const float* Ub = U + (size_t)b * TT * 3072 + z * 1536 + h4;
    const float* xb = x + (size_t)b * TT * 1024 + z * 512 + h4;
    float* ob       = out + (size_t)b * TT * 1024 + z * 512 + h4;
    float4 c = ld4(&cstart[((size_t)s << 14) + (ci << 2)]);
#pragma unroll 2
    for (int q = 0; q < CL; q++) {
        int n = s * CL + q;
        int t = z ? (TT - 1 - n) : n;
        size_t o = (size_t)t * 3072;
        float4 g  = ld4(Ub + o);
        float4 f  = ld4(Ub + o + 512);
        float4 r  = ld4(Ub + o + 1024);
        float4 xv = ld4(xb + (size_t)t * 1024);
        float4 hv;
        STEPC(c.x, g.x, f.x, r.x, xv.x, bf.x, br.x, hv.x);
        STEPC(c.y, g.y, f.y, r.y, xv.y, bf.y, br.y, hv.y);
        STEPC(c.z, g.z, f.z, r.z, xv.z, bf.z, br.z, hv.z);
        STEPC(c.w, g.w, f.w, r.w, xv.w, bf.w, br.w, hv.w);
        *(float4*)(ob + (size_t)t * 1024) = hv;
    }
    if (s == NCH - 1)
        *(float4*)(out + (size_t)BB * TT * 1024 + b * 1024 + z * 512 + h4) = c;
}

// ---------------------------------------------------------------------------
// Workspace (total 415,236,096 B — same as the passing round-5 layout):
//   U   : [0, 402,653,184)
//   Bth : [402,653,184, 408,944,640)   Btl : [408,944,640, 415,236,096)
//   F/Cp/cst (2 MB each) alias over Bth/Btl (dead after GEMM).
// ---------------------------------------------------------------------------
extern "C" void kernel_launch(void* const* d_in, const int* in_sizes, int n_in,
                              void* d_out, int out_size, void* d_ws,
                              size_t ws_size, hipStream_t stream) {
    const float* x    = (const float*)d_in[0];
    const float* W    = (const float*)d_in[1];
    const float* bias = (const float*)d_in[2];
    float* out        = (float*)d_out;

    char* ws    = (char*)d_ws;
    float* U    = (float*)ws;
    ushort* Bth = (ushort*)(ws + 402653184UL);
    ushort* Btl = (ushort*)(ws + 408944640UL);
    float* F    = (float*)(ws + 402653184UL);  // alias (B dead after GEMM)
    float* Cp   = (float*)(ws + 404750336UL);
    float* cst  = (float*)(ws + 406847488UL);

    convert_W<<<12288, 256, 0, stream>>>(W, Bth, Btl);

    dim3 grid(256, 24);
    gemm_bf16split<<<grid, 256, 0, stream>>>(x, Bth, Btl, U);

    scanA<<<512, 256, 0, stream>>>(U, bias, F, Cp);
    scanB<<<16, 256, 0, stream>>>(F, Cp, cst);
    scanC<<<512, 256, 0, stream>>>(U, x, bias, cst, out);
}

// Round 7
// 1006.600 us; speedup vs baseline: 1.0108x; 1.0108x over previous
//
#include <hip/hip_runtime.h>
#include <cstdint>

typedef unsigned int uint;
typedef unsigned short ushort;
typedef __attribute__((ext_vector_type(8))) __bf16 bf16x8;
typedef __attribute__((ext_vector_type(4))) float f32x4;
typedef __attribute__((ext_vector_type(4))) ushort us4;

#define BB 16
#define TT 2048
#define DD 1024
#define HH 512
// GEMM: M = 32768, N = 3072, K = 1024

// ---------------------------------------------------------------------------
// helpers
// ---------------------------------------------------------------------------
__device__ inline ushort f2bf(float f) {
    uint u = __float_as_uint(f);
    u += 0x7FFF + ((u >> 16) & 1);  // RNE
    return (ushort)(u >> 16);
}
__device__ inline float bf2f(ushort b) {
    return __uint_as_float(((uint)b) << 16);
}
__device__ inline float sigm(float x) { return 1.f / (1.f + __expf(-x)); }
__device__ inline float4 ld4(const float* p) { return *(const float4*)p; }

__device__ inline void gload16(const void* g, void* l) {
    __builtin_amdgcn_global_load_lds(
        (const __attribute__((address_space(1))) uint*)g,
        (__attribute__((address_space(3))) uint*)l, 16, 0, 0);
}

// ---------------------------------------------------------------------------
// W (D,2,H,3) f32 -> Bth, Btl bf16 [N=3072][K=1024], LDS tile-transpose.
// n = z*1536 + gate*512 + h ;  Bt[n][d] = W[d][z][h][gate]
// Block: 64 d-rows x (64 h x 3 gates = 192 contiguous c-cols) of W.
// Reads coalesced along c; writes coalesced along d (128 B per 16 lanes).
// ---------------------------------------------------------------------------
__global__ __launch_bounds__(256) void convert_W(const float* __restrict__ W,
                                                 ushort* __restrict__ Bth,
                                                 ushort* __restrict__ Btl) {
    __shared__ float tile[64][193];  // +1 pad
    const int bid = blockIdx.x;       // 256 blocks
    const int d0  = (bid >> 4) * 64;  // 16 d-tiles
    const int z   = (bid >> 3) & 1;
    const int h0  = (bid & 7) * 64;   // 8 h-tiles

    const float* Wb = W + z * 1536 + h0 * 3;
#pragma unroll
    for (int i = 0; i < 12; i++) {
        int f   = i * 256 + threadIdx.x;  // 0..3071
        int row = f / 48;                 // 0..63  (d-local)
        int c4  = f % 48;                 // float4 col
        float4 v = ld4(Wb + (size_t)(d0 + row) * 3072 + c4 * 4);
        tile[row][c4 * 4 + 0] = v.x;
        tile[row][c4 * 4 + 1] = v.y;
        tile[row][c4 * 4 + 2] = v.z;
        tile[row][c4 * 4 + 3] = v.w;
    }
    __syncthreads();

    const int dd4 = (threadIdx.x & 15) * 4;
#pragma unroll
    for (int g = 0; g < 3; g++) {
#pragma unroll
        for (int j = 0; j < 4; j++) {
            int nn = (threadIdx.x >> 4) + j * 16;  // 0..63 (h-local)
            us4 hi, lo;
#pragma unroll
            for (int i = 0; i < 4; i++) {
                float wv = tile[dd4 + i][nn * 3 + g];
                ushort h = f2bf(wv);
                hi[i]    = h;
                lo[i]    = f2bf(wv - bf2f(h));
            }
            size_t n   = (size_t)z * 1536 + g * 512 + h0 + nn;
            size_t off = (n << 10) + d0 + dd4;
            *(us4*)(Bth + off) = hi;
            *(us4*)(Btl + off) = lo;
        }
    }
}

// ---------------------------------------------------------------------------
// split-bf16 MFMA GEMM with fused A conversion (round-5 structure, proven
// 620 us / MfmaUtil 48.7 / 0 bank conflicts; round-6 A-prefetch regressed
// and was reverted).
// C[M][3072] ~= (Ah+Al)(Bh+Bl)  (Ah·Bh + Ah·Bl + Al·Bh; Al·Bl dropped)
// 128x128 tile, BK=32, 256 threads = 4 waves (2x2), each wave 64x64 = 4x4
// 16x16x32 fragments, 3 MFMA per fragment pair.
// LDS: Ah | Al | Bh | Bl, each [128][32] bf16, 16B chunks XOR-swizzled by
// ((row>>1)&3) on both write and read (cancels logically; 2-way = free).
// ---------------------------------------------------------------------------
__global__ __launch_bounds__(256, 2) void gemm_bf16split(
    const float* __restrict__ x, const ushort* __restrict__ Bth,
    const ushort* __restrict__ Btl, float* __restrict__ C) {
    __shared__ ushort lds[4 * 128 * 32];  // 32 KB

    const int t    = threadIdx.x;
    const int w    = t >> 6;
    const int lane = t & 63;
    const size_t m0 = (size_t)blockIdx.x * 128;
    const size_t n0 = (size_t)blockIdx.y * 128;
    const int wm = w >> 1, wn = w & 1;

    f32x4 acc[4][4];
#pragma unroll
    for (int i = 0; i < 4; i++)
#pragma unroll
        for (int j = 0; j < 4; j++) acc[i][j] = (f32x4)(0.f);

    const int srow  = w * 32 + (lane >> 2);
    const int kphys = lane & 3;
    const int frow  = lane & 15;
    const int fkoff = (((lane >> 4) ^ ((frow >> 1) & 3)) << 3);  // ushort off

    for (int k0 = 0; k0 < 1024; k0 += 32) {
        // ---- A tile: load 128x32 f32 of x into regs (4 float4/thread) ----
        float4 xv[4];
#pragma unroll
        for (int p = 0; p < 4; p++) {
            int ridx = p * 256 + t;  // 0..1023
            int row  = ridx >> 3;    // 0..127
            int kq   = ridx & 7;     // float4 index
            xv[p] = ld4(x + (m0 + row) * 1024 + k0 + kq * 4);
        }
        // ---- B tiles: async global->LDS, pre-swizzled source ----
#pragma unroll
        for (int arr = 0; arr < 2; arr++) {
            const ushort* G = arr ? Btl : Bth;
#pragma unroll
            for (int c = 0; c < 2; c++) {
                const int row = srow + c * 16;
                const int kcl = kphys ^ ((row >> 1) & 3);
                const ushort* src = G + ((n0 + row) << 10) + k0 + (kcl << 3);
                char* dst = (char*)lds + (2 + arr) * 8192 +
                            (w * 32 + c * 16) * 64 + lane * 16;
                gload16(src, dst);
            }
        }
        // ---- convert A to hi/lo bf16, swizzled ds_write (8B each) ----
#pragma unroll
        for (int p = 0; p < 4; p++) {
            int ridx = p * 256 + t;
            int row  = ridx >> 3;
            int kq   = ridx & 7;
            int off  = row * 64 + (((kq >> 1) ^ ((row >> 1) & 3)) << 4) +
                       ((kq & 1) << 3);
            float vf[4] = {xv[p].x, xv[p].y, xv[p].z, xv[p].w};
            us4 hi, lo;
#pragma unroll
            for (int j = 0; j < 4; j++) {
                ushort h = f2bf(vf[j]);
                hi[j]    = h;
                lo[j]    = f2bf(vf[j] - bf2f(h));
            }
            *(us4*)((char*)lds + off)        = hi;
            *(us4*)((char*)lds + 8192 + off) = lo;
        }
        __syncthreads();  // drains lgkm (ds_write) + vm (global_load_lds)

        bf16x8 fa[4], fal[4], fb[4], fbl[4];
#pragma unroll
        for (int i = 0; i < 4; i++) {
            const int ra = (wm * 64 + i * 16 + frow) * 32;
            const int rb = (wn * 64 + i * 16 + frow) * 32;
            fa[i]  = *(const bf16x8*)&lds[0 * 4096 + ra + fkoff];
            fal[i] = *(const bf16x8*)&lds[1 * 4096 + ra + fkoff];
            fb[i]  = *(const bf16x8*)&lds[2 * 4096 + rb + fkoff];
            fbl[i] = *(const bf16x8*)&lds[3 * 4096 + rb + fkoff];
        }
#pragma unroll
        for (int i = 0; i < 4; i++)
#pragma unroll
            for (int j = 0; j < 4; j++) {
                acc[i][j] = __builtin_amdgcn_mfma_f32_16x16x32_bf16(
                    fa[i], fb[j], acc[i][j], 0, 0, 0);
                acc[i][j] = __builtin_amdgcn_mfma_f32_16x16x32_bf16(
                    fa[i], fbl[j], acc[i][j], 0, 0, 0);
                acc[i][j] = __builtin_amdgcn_mfma_f32_16x16x32_bf16(
                    fal[i], fb[j], acc[i][j], 0, 0, 0);
            }
        __syncthreads();  // protect LDS before next stage
    }

    // epilogue: C/D layout col=lane&15 (n), row=(lane>>4)*4+reg (m)
    const int ccol = lane & 15;
    const int crow = (lane >> 4) * 4;
#pragma unroll
    for (int i = 0; i < 4; i++) {
        const size_t mrow = m0 + wm * 64 + i * 16 + crow;
#pragma unroll
        for (int j = 0; j < 4; j++) {
            const size_t ncol = n0 + wn * 64 + j * 16 + ccol;
            float* Cp = C + mrow * 3072 + ncol;
#pragma unroll
            for (int r = 0; r < 4; r++) Cp[(size_t)r * 3072] = acc[i][j][r];
        }
    }
}

// ---------------------------------------------------------------------------
// Scan, vectorized 4 channels/thread (float4). 64 chunks of 32 steps
// (NCH=64 -> 16 waves/CU for latency hiding).
// Thread map: tid = s*4096 + ci; ci = b*256 + z*128 + (h4/4).
// U[(b*T+t)*3072 + z*1536 + gate*512 + h], gate 0=g 1=f 2=r.
// logical step n; physical t = z ? T-1-n : n.
// ---------------------------------------------------------------------------
#define SCH 16384
#define NCH 64
#define CL 32

#define STEPA(CC, FA, G, FP, BF)          \
    {                                     \
        float ff = sigm((FP) + (BF));     \
        CC = ff * CC + (1.f - ff) * (G);  \
        FA *= ff;                         \
    }

#define STEPC(CC, G, FP, RP, XV, BF, BR, OUT)       \
    {                                               \
        float ff = sigm((FP) + (BF));               \
        float rr = sigm((RP) + (BR));               \
        CC = ff * CC + (1.f - ff) * (G);            \
        float e  = __expf(2.f * CC);                \
        float th = 1.f - 2.f / (e + 1.f);           \
        OUT = rr * th + (1.f - rr) * (XV);          \
    }

__global__ __launch_bounds__(256) void scanA(const float* __restrict__ U,
                                             const float* __restrict__ bias,
                                             float* __restrict__ F,
                                             float* __restrict__ Cp) {
    int tid = blockIdx.x * 256 + threadIdx.x;  // 0..262143
    int s   = tid >> 12;                       // 0..63
    int ci  = tid & 4095;
    int b = ci >> 8, z = (ci >> 7) & 1, h4 = (ci & 127) << 2;
    float4 bf = ld4(&bias[z * 1024 + h4]);
    const float* Ub = U + (size_t)b * TT * 3072 + z * 1536 + h4;
    float4 c  = {0.f, 0.f, 0.f, 0.f};
    float4 Fa = {1.f, 1.f, 1.f, 1.f};
#pragma unroll 4
    for (int q = 0; q < CL; q++) {
        int n = s * CL + q;
        int t = z ? (TT - 1 - n) : n;
        size_t o = (size_t)t * 3072;
        float4 g = ld4(Ub + o);
        float4 f = ld4(Ub + o + 512);
        STEPA(c.x, Fa.x, g.x, f.x, bf.x);
        STEPA(c.y, Fa.y, g.y, f.y, bf.y);
        STEPA(c.z, Fa.z, g.z, f.z, bf.z);
        STEPA(c.w, Fa.w, g.w, f.w, bf.w);
    }
    *(float4*)&F[((size_t)s << 14) + (ci << 2)]  = Fa;
    *(float4*)&Cp[((size_t)s << 14) + (ci << 2)] = c;
}

__global__ __launch_bounds__(256) void scanB(const float* __restrict__ F,
                                             const float* __restrict__ Cp,
                                             float* __restrict__ cstart) {
    int ci = blockIdx.x * 256 + threadIdx.x;  // 0..4095
    float4 c = {0.f, 0.f, 0.f, 0.f};
    for (int s = 0; s < NCH; s++) {
        size_t o = ((size_t)s << 14) + (ci << 2);
        *(float4*)&cstart[o] = c;
        float4 Fv = ld4(&F[o]);
        float4 Cv = ld4(&Cp[o]);
        c.x = Fv.x * c.x + Cv.x;
        c.y = Fv.y * c.y + Cv.y;
        c.z = Fv.z * c.z + Cv.z;
        c.w = Fv.w * c.w + Cv.w;
    }
}

__global__ __launch_bounds__(256) void scanC(const float* __restrict__ U,
                                             const float* __restrict__ x,
                                             const float* __restrict__ bias,
                                             const float* __restrict__ cstart,
                                             float* __restrict__ out) {
    int tid = blockIdx.x * 256 + threadIdx.x;  // 0..262143
    int s   = tid >> 12;                       // 0..63
    int ci  = tid & 4095;
    int b = ci >> 8, z = (ci >> 7) & 1, h4 = (ci & 127) << 2;
    float4 bf = ld4(&bias[z * 1024 + h4]);
    float4 br = ld4(&bias[z * 1024 + 512 + h4]);
    const float* Ub = U + (size_t)b * TT * 3072 + z * 1536 + h4;
    const float* xb = x + (size_t)b * TT * 1024 + z * 512 + h4;
    float* ob       = out + (size_t)b * TT * 1024 + z * 512 + h4;
    float4 c = ld4(&cstart[((size_t)s << 14) + (ci << 2)]);
#pragma unroll 2
    for (int q = 0; q < CL; q++) {
        int n = s * CL + q;
        int t = z ? (TT - 1 - n) : n;
        size_t o = (size_t)t * 3072;
        float4 g  = ld4(Ub + o);
        float4 f  = ld4(Ub + o + 512);
        float4 r  = ld4(Ub + o + 1024);
        float4 xv = ld4(xb + (size_t)t * 1024);
        float4 hv;
        STEPC(c.x, g.x, f.x, r.x, xv.x, bf.x, br.x, hv.x);
        STEPC(c.y, g.y, f.y, r.y, xv.y, bf.y, br.y, hv.y);
        STEPC(c.z, g.z, f.z, r.z, xv.z, bf.z, br.z, hv.z);
        STEPC(c.w, g.w, f.w, r.w, xv.w, bf.w, br.w, hv.w);
        *(float4*)(ob + (size_t)t * 1024) = hv;
    }
    if (s == NCH - 1)
        *(float4*)(out + (size_t)BB * TT * 1024 + b * 1024 + z * 512 + h4) = c;
}

// ---------------------------------------------------------------------------
// Workspace (total 415,236,096 B — same as the passing round-5 layout):
//   U   : [0, 402,653,184)
//   Bth : [402,653,184, 408,944,640)   Btl : [408,944,640, 415,236,096)
//   F/Cp/cst (4 MB each = 12.58 MB) alias exactly over Bth/Btl (dead after
//   GEMM).
// ---------------------------------------------------------------------------
extern "C" void kernel_launch(void* const* d_in, const int* in_sizes, int n_in,
                              void* d_out, int out_size, void* d_ws,
                              size_t ws_size, hipStream_t stream) {
    const float* x    = (const float*)d_in[0];
    const float* W    = (const float*)d_in[1];
    const float* bias = (const float*)d_in[2];
    float* out        = (float*)d_out;

    char* ws    = (char*)d_ws;
    float* U    = (float*)ws;
    ushort* Bth = (ushort*)(ws + 402653184UL);
    ushort* Btl = (ushort*)(ws + 408944640UL);
    float* F    = (float*)(ws + 402653184UL);  // alias (B dead after GEMM)
    float* Cp   = (float*)(ws + 406847488UL);
    float* cst  = (float*)(ws + 411041792UL);

    convert_W<<<256, 256, 0, stream>>>(W, Bth, Btl);

    dim3 grid(256, 24);
    gemm_bf16split<<<grid, 256, 0, stream>>>(x, Bth, Btl, U);

    scanA<<<1024, 256, 0, stream>>>(U, bias, F, Cp);
    scanB<<<16, 256, 0, stream>>>(F, Cp, cst);
    scanC<<<1024, 256, 0, stream>>>(U, x, bias, cst, out);
}

// Round 8
// 947.178 us; speedup vs baseline: 1.0742x; 1.0627x over previous
//
#include <hip/hip_runtime.h>
#include <cstdint>

typedef unsigned int uint;
typedef unsigned short ushort;
typedef __attribute__((ext_vector_type(8))) __bf16 bf16x8;
typedef __attribute__((ext_vector_type(4))) float f32x4;
typedef __attribute__((ext_vector_type(4))) ushort us4;

#define BB 16
#define TT 2048
#define DD 1024
#define HH 512
// GEMM: M = 32768, N = 3072, K = 1024

// ---------------------------------------------------------------------------
// helpers
// ---------------------------------------------------------------------------
__device__ inline ushort f2bf(float f) {
    uint u = __float_as_uint(f);
    u += 0x7FFF + ((u >> 16) & 1);  // RNE
    return (ushort)(u >> 16);
}
__device__ inline float bf2f(ushort b) {
    return __uint_as_float(((uint)b) << 16);
}
__device__ inline float sigm(float x) { return 1.f / (1.f + __expf(-x)); }
__device__ inline float4 ld4(const float* p) { return *(const float4*)p; }

__device__ inline void gload16(const void* g, void* l) {
    __builtin_amdgcn_global_load_lds(
        (const __attribute__((address_space(1))) uint*)g,
        (__attribute__((address_space(3))) uint*)l, 16, 0, 0);
}

// ---------------------------------------------------------------------------
// W (D,2,H,3) f32 -> Bth, Btl bf16 [N=3072][K=1024], LDS tile-transpose.
// (round-7 version, kept)
// ---------------------------------------------------------------------------
__global__ __launch_bounds__(256) void convert_W(const float* __restrict__ W,
                                                 ushort* __restrict__ Bth,
                                                 ushort* __restrict__ Btl) {
    __shared__ float tile[64][193];  // +1 pad
    const int bid = blockIdx.x;       // 256 blocks
    const int d0  = (bid >> 4) * 64;  // 16 d-tiles
    const int z   = (bid >> 3) & 1;
    const int h0  = (bid & 7) * 64;   // 8 h-tiles

    const float* Wb = W + z * 1536 + h0 * 3;
#pragma unroll
    for (int i = 0; i < 12; i++) {
        int f   = i * 256 + threadIdx.x;  // 0..3071
        int row = f / 48;                 // 0..63  (d-local)
        int c4  = f % 48;                 // float4 col
        float4 v = ld4(Wb + (size_t)(d0 + row) * 3072 + c4 * 4);
        tile[row][c4 * 4 + 0] = v.x;
        tile[row][c4 * 4 + 1] = v.y;
        tile[row][c4 * 4 + 2] = v.z;
        tile[row][c4 * 4 + 3] = v.w;
    }
    __syncthreads();

    const int dd4 = (threadIdx.x & 15) * 4;
#pragma unroll
    for (int g = 0; g < 3; g++) {
#pragma unroll
        for (int j = 0; j < 4; j++) {
            int nn = (threadIdx.x >> 4) + j * 16;  // 0..63 (h-local)
            us4 hi, lo;
#pragma unroll
            for (int i = 0; i < 4; i++) {
                float wv = tile[dd4 + i][nn * 3 + g];
                ushort h = f2bf(wv);
                hi[i]    = h;
                lo[i]    = f2bf(wv - bf2f(h));
            }
            size_t n   = (size_t)z * 1536 + g * 512 + h0 + nn;
            size_t off = (n << 10) + d0 + dd4;
            *(us4*)(Bth + off) = hi;
            *(us4*)(Btl + off) = lo;
        }
    }
}

// ---------------------------------------------------------------------------
// split-bf16 MFMA GEMM, 128x256 tile, BK=32, 512 threads = 8 waves (2m x 4n),
// wave tile 64x64 = 4x4 16x16x32 frags, 3 MFMA per frag pair (numerics
// identical to the round-5/7 kernel).
// Rationale vs 128x128: per-thread A-conversion VALU halves (8 floats/step),
// x loaded+converted 12x instead of 24x, LDS 48 KB -> 3 blocks/CU.
// LDS arrays: Ah[128][32] Al[128][32] Bh[256][32] Bl[256][32] bf16; 16B
// k-chunks XOR-swizzled by ((row>>1)&3) on write and read (cancels; 2-way
// bank alias = free; measured 0 conflicts in r5/r7).
// ---------------------------------------------------------------------------
__global__ __launch_bounds__(512, 4) void gemm_bf16split(
    const float* __restrict__ x, const ushort* __restrict__ Bth,
    const ushort* __restrict__ Btl, float* __restrict__ C) {
    __shared__ ushort lds[6 * 128 * 32];  // 48 KB: Ah|Al|Bh|Bl

    const int t    = threadIdx.x;
    const int w    = t >> 6;
    const int lane = t & 63;
    const size_t m0 = (size_t)blockIdx.x * 128;
    const size_t n0 = (size_t)blockIdx.y * 256;
    const int wm = w >> 2, wn = w & 3;

    f32x4 acc[4][4];
#pragma unroll
    for (int i = 0; i < 4; i++)
#pragma unroll
        for (int j = 0; j < 4; j++) acc[i][j] = (f32x4)(0.f);

    // B staging: per array 2 calls; call c, wave w covers rows
    // c*128 + w*16 + (lane>>2); physical chunk = lane&3.
    const int srow  = w * 16 + (lane >> 2);
    const int kphys = lane & 3;

    // frag read: row (lane&15); logical chunk = lane>>4,
    // physical = (lane>>4) ^ ((row>>1)&3)
    const int frow  = lane & 15;
    const int fkoff = (((lane >> 4) ^ ((frow >> 1) & 3)) << 3);  // ushort off

    for (int k0 = 0; k0 < 1024; k0 += 32) {
        // ---- A tile: 128x32 f32 of x -> regs (2 float4/thread) ----
        float4 xv[2];
#pragma unroll
        for (int p = 0; p < 2; p++) {
            int ridx = p * 512 + t;  // 0..1023
            int row  = ridx >> 3;    // 0..127
            int kq   = ridx & 7;     // float4 index
            xv[p] = ld4(x + (m0 + row) * 1024 + k0 + kq * 4);
        }
        // ---- B tiles: async global->LDS, pre-swizzled source ----
#pragma unroll
        for (int arr = 0; arr < 2; arr++) {
            const ushort* G = arr ? Btl : Bth;
#pragma unroll
            for (int c = 0; c < 2; c++) {
                const int row = c * 128 + srow;
                const int kcl = kphys ^ ((row >> 1) & 3);
                const ushort* src = G + ((n0 + row) << 10) + k0 + (kcl << 3);
                char* dst = (char*)lds + (arr ? 32768 : 16384) +
                            (c * 128 + w * 16) * 64 + lane * 16;
                gload16(src, dst);
            }
        }
        // ---- convert A to hi/lo bf16, swizzled ds_write (8B each) ----
#pragma unroll
        for (int p = 0; p < 2; p++) {
            int ridx = p * 512 + t;
            int row  = ridx >> 3;
            int kq   = ridx & 7;
            int off  = row * 64 + (((kq >> 1) ^ ((row >> 1) & 3)) << 4) +
                       ((kq & 1) << 3);
            float vf[4] = {xv[p].x, xv[p].y, xv[p].z, xv[p].w};
            us4 hi, lo;
#pragma unroll
            for (int j = 0; j < 4; j++) {
                ushort h = f2bf(vf[j]);
                hi[j]    = h;
                lo[j]    = f2bf(vf[j] - bf2f(h));
            }
            *(us4*)((char*)lds + off)        = hi;
            *(us4*)((char*)lds + 8192 + off) = lo;
        }
        __syncthreads();  // drains lgkm (ds_write) + vm (global_load_lds)

        bf16x8 fa[4], fal[4], fb[4], fbl[4];
#pragma unroll
        for (int i = 0; i < 4; i++) {
            const int ra = (wm * 64 + i * 16 + frow) * 32;
            const int rb = (wn * 64 + i * 16 + frow) * 32;
            fa[i]  = *(const bf16x8*)&lds[0 + ra + fkoff];
            fal[i] = *(const bf16x8*)&lds[4096 + ra + fkoff];
            fb[i]  = *(const bf16x8*)&lds[8192 + rb + fkoff];
            fbl[i] = *(const bf16x8*)&lds[16384 + rb + fkoff];
        }
#pragma unroll
        for (int i = 0; i < 4; i++)
#pragma unroll
            for (int j = 0; j < 4; j++) {
                acc[i][j] = __builtin_amdgcn_mfma_f32_16x16x32_bf16(
                    fa[i], fb[j], acc[i][j], 0, 0, 0);
                acc[i][j] = __builtin_amdgcn_mfma_f32_16x16x32_bf16(
                    fa[i], fbl[j], acc[i][j], 0, 0, 0);
                acc[i][j] = __builtin_amdgcn_mfma_f32_16x16x32_bf16(
                    fal[i], fb[j], acc[i][j], 0, 0, 0);
            }
        __syncthreads();  // protect LDS before next stage
    }

    // epilogue: C/D layout col=lane&15 (n), row=(lane>>4)*4+reg (m)
    const int ccol = lane & 15;
    const int crow = (lane >> 4) * 4;
#pragma unroll
    for (int i = 0; i < 4; i++) {
        const size_t mrow = m0 + wm * 64 + i * 16 + crow;
#pragma unroll
        for (int j = 0; j < 4; j++) {
            const size_t ncol = n0 + wn * 64 + j * 16 + ccol;
            float* Cp = C + mrow * 3072 + ncol;
#pragma unroll
            for (int r = 0; r < 4; r++) Cp[(size_t)r * 3072] = acc[i][j][r];
        }
    }
}

// ---------------------------------------------------------------------------
// Scan, vectorized 4 channels/thread (float4). 32 chunks of 64 steps
// (round-6 measured-better config; NCH=64 regressed in r7).
// U[(b*T+t)*3072 + z*1536 + gate*512 + h], gate 0=g 1=f 2=r.
// ---------------------------------------------------------------------------
#define SCH 16384
#define NCH 32
#define CL 64

#define STEPA(CC, FA, G, FP, BF)          \
    {                                     \
        float ff = sigm((FP) + (BF));     \
        CC = ff * CC + (1.f - ff) * (G);  \
        FA *= ff;                         \
    }

#define STEPC(CC, G, FP, RP, XV, BF, BR, OUT)       \
    {                                               \
        float ff = sigm((FP) + (BF));               \
        float rr = sigm((RP) + (BR));               \
        CC = ff * CC + (1.f - ff) * (G);            \
        float e  = __expf(2.f * CC);                \
        float th = 1.f - 2.f / (e + 1.f);           \
        OUT = rr * th + (1.f - rr) * (XV);          \
    }

__global__ __launch_bounds__(256) void scanA(const float* __restrict__ U,
                                             const float* __restrict__ bias,
                                             float* __restrict__ F,
                                             float* __restrict__ Cp) {
    int tid = blockIdx.x * 256 + threadIdx.x;  // 0..131071
    int s   = tid >> 12;
    int ci  = tid & 4095;
    int b = ci >> 8, z = (ci >> 7) & 1, h4 = (ci & 127) << 2;
    float4 bf = ld4(&bias[z * 1024 + h4]);
    const float* Ub = U + (size_t)b * TT * 3072 + z * 1536 + h4;
    float4 c  = {0.f, 0.f, 0.f, 0.f};
    float4 Fa = {1.f, 1.f, 1.f, 1.f};
#pragma unroll 4
    for (int q = 0; q < CL; q++) {
        int n = s * CL + q;
        int t = z ? (TT - 1 - n) : n;
        size_t o = (size_t)t * 3072;
        float4 g = ld4(Ub + o);
        float4 f = ld4(Ub + o + 512);
        STEPA(c.x, Fa.x, g.x, f.x, bf.x);
        STEPA(c.y, Fa.y, g.y, f.y, bf.y);
        STEPA(c.z, Fa.z, g.z, f.z, bf.z);
        STEPA(c.w, Fa.w, g.w, f.w, bf.w);
    }
    *(float4*)&F[((size_t)s << 14) + (ci << 2)]  = Fa;
    *(float4*)&Cp[((size_t)s << 14) + (ci << 2)] = c;
}

__global__ __launch_bounds__(256) void scanB(const float* __restrict__ F,
                                             const float* __restrict__ Cp,
                                             float* __restrict__ cstart) {
    int ci = blockIdx.x * 256 + threadIdx.x;  // 0..4095
    float4 c = {0.f, 0.f, 0.f, 0.f};
    for (int s = 0; s < NCH; s++) {
        size_t o = ((size_t)s << 14) + (ci << 2);
        *(float4*)&cstart[o] = c;
        float4 Fv = ld4(&F[o]);
        float4 Cv = ld4(&Cp[o]);
        c.x = Fv.x * c.x + Cv.x;
        c.y = Fv.y * c.y + Cv.y;
        c.z = Fv.z * c.z + Cv.z;
        c.w = Fv.w * c.w + Cv.w;
    }
}

__global__ __launch_bounds__(256) void scanC(const float* __restrict__ U,
                                             const float* __restrict__ x,
                                             const float* __restrict__ bias,
                                             const float* __restrict__ cstart,
                                             float* __restrict__ out) {
    int tid = blockIdx.x * 256 + threadIdx.x;  // 0..131071
    int s   = tid >> 12;
    int ci  = tid & 4095;
    int b = ci >> 8, z = (ci >> 7) & 1, h4 = (ci & 127) << 2;
    float4 bf = ld4(&bias[z * 1024 + h4]);
    float4 br = ld4(&bias[z * 1024 + 512 + h4]);
    const float* Ub = U + (size_t)b * TT * 3072 + z * 1536 + h4;
    const float* xb = x + (size_t)b * TT * 1024 + z * 512 + h4;
    float* ob       = out + (size_t)b * TT * 1024 + z * 512 + h4;
    float4 c = ld4(&cstart[((size_t)s << 14) + (ci << 2)]);
#pragma unroll 2
    for (int q = 0; q < CL; q++) {
        int n = s * CL + q;
        int t = z ? (TT - 1 - n) : n;
        size_t o = (size_t)t * 3072;
        float4 g  = ld4(Ub + o);
        float4 f  = ld4(Ub + o + 512);
        float4 r  = ld4(Ub + o + 1024);
        float4 xv = ld4(xb + (size_t)t * 1024);
        float4 hv;
        STEPC(c.x, g.x, f.x, r.x, xv.x, bf.x, br.x, hv.x);
        STEPC(c.y, g.y, f.y, r.y, xv.y, bf.y, br.y, hv.y);
        STEPC(c.z, g.z, f.z, r.z, xv.z, bf.z, br.z, hv.z);
        STEPC(c.w, g.w, f.w, r.w, xv.w, bf.w, br.w, hv.w);
        *(float4*)(ob + (size_t)t * 1024) = hv;
    }
    if (s == NCH - 1)
        *(float4*)(out + (size_t)BB * TT * 1024 + b * 1024 + z * 512 + h4) = c;
}

// ---------------------------------------------------------------------------
// Workspace (total 415,236,096 B — proven layout):
//   U   : [0, 402,653,184)
//   Bth : [402,653,184, 408,944,640)   Btl : [408,944,640, 415,236,096)
//   F/Cp/cst (2 MB each) alias over Bth/Btl (dead after GEMM).
// ---------------------------------------------------------------------------
extern "C" void kernel_launch(void* const* d_in, const int* in_sizes, int n_in,
                              void* d_out, int out_size, void* d_ws,
                              size_t ws_size, hipStream_t stream) {
    const float* x    = (const float*)d_in[0];
    const float* W    = (const float*)d_in[1];
    const float* bias = (const float*)d_in[2];
    float* out        = (float*)d_out;

    char* ws    = (char*)d_ws;
    float* U    = (float*)ws;
    ushort* Bth = (ushort*)(ws + 402653184UL);
    ushort* Btl = (ushort*)(ws + 408944640UL);
    float* F    = (float*)(ws + 402653184UL);  // alias (B dead after GEMM)
    float* Cp   = (float*)(ws + 404750336UL);
    float* cst  = (float*)(ws + 406847488UL);

    convert_W<<<256, 256, 0, stream>>>(W, Bth, Btl);

    dim3 grid(256, 12);
    gemm_bf16split<<<grid, 512, 0, stream>>>(x, Bth, Btl, U);

    scanA<<<512, 256, 0, stream>>>(U, bias, F, Cp);
    scanB<<<16, 256, 0, stream>>>(F, Cp, cst);
    scanC<<<512, 256, 0, stream>>>(U, x, bias, cst, out);
}